// Round 1
// baseline (181.991 us; speedup 1.0000x reference)
//
#include <hip/hip_runtime.h>

// OrdLoss: N=2, C=16, D=32, H=128, W=128
// out = [ sum_{valid m} ( sum_{c<=t} log(clip(p)) + sum_{c>t} log(clip(1-p)) ) ] / ( -sum(valid) )
//
// R6: single-dispatch fusion (last-block-done reduction).
// Session context: per-iteration time = ~120 us harness poison fills
// (3 x 40 us, 268 MB each, 82-84% HBM peak — untouchable) + ~16 us of our
// work. Main kernel is at the 76 MB compulsory-traffic floor (~12-13 us);
// the only remaining lever is the second dispatch (ordloss_reduce):
// graph kernel-node launch + 1-block 8 KB kernel ~= 3-4 us. Fuse it into
// the main kernel: each block publishes its partial with agent-scope
// stores + __threadfence, takes a ticket via device-scope atomicAdd; the
// last block re-reads all 1024 partials (agent-scope loads, same
// double-precision summation order as the old reduce kernel => bit-identical
// result) and writes the scalar. Ticket is zeroed by a 4-byte
// hipMemsetAsync node each iteration (ws is re-poisoned by the harness, so
// in-kernel self-reset is unsafe).
//
// Main-kernel structure unchanged from the 135.9 us best: 1024 blocks x
// 256 threads, 4 voxels/thread, all 18 loads issued before compute,
// 64 logs over 4 independent accumulator chains, wave64 shuffle reduce.

constexpr int  kC     = 16;
constexpr int  kDHW   = 32 * 128 * 128;   // 524288 = 2^19
constexpr long kM     = 2L * kDHW;        // 1048576 voxels
constexpr int  kBlock = 256;
constexpr int  kVox   = 4;                // voxels per thread (one float4 per channel)
constexpr int  kGrid  = (int)(kM / kVox / kBlock);   // 1024 blocks

__global__ __launch_bounds__(kBlock)
void ordloss_fused(const float* __restrict__ pred,
                   const int*   __restrict__ target,
                   const int*   __restrict__ mask,
                   float*       __restrict__ bsum,
                   int*         __restrict__ bcnt,
                   unsigned*    __restrict__ ticket,
                   float*       __restrict__ out) {
    const int  tid  = blockIdx.x * kBlock + threadIdx.x;
    const long base = (long)tid * kVox;
    const int  n    = (int)(base >> 19);             // base / kDHW
    const int  sp   = (int)(base & (kDHW - 1));

    // ---- issue ALL loads up front ----
    const int4 mk = *reinterpret_cast<const int4*>(mask + base);
    const int4 tg = *reinterpret_cast<const int4*>(target + ((size_t)n << 23) + sp);
    const float* pb = pred + ((size_t)n << 23) + sp; // n*16*kDHW
    float4 p[kC];
    #pragma unroll
    for (int c = 0; c < kC; ++c)
        p[c] = *reinterpret_cast<const float4*>(pb + ((size_t)c << 19));

    // ---- compute: 64 logs, 4 independent accumulator chains ----
    float acc0 = 0.f, acc1 = 0.f, acc2 = 0.f, acc3 = 0.f;
    #pragma unroll
    for (int c = 0; c < kC; ++c) {
        float x0 = (c <= tg.x) ? p[c].x : 1.0f - p[c].x;
        float x1 = (c <= tg.y) ? p[c].y : 1.0f - p[c].y;
        float x2 = (c <= tg.z) ? p[c].z : 1.0f - p[c].z;
        float x3 = (c <= tg.w) ? p[c].w : 1.0f - p[c].w;
        acc0 += __logf(fmaxf(x0, 1e-8f));   // p in [0,1): only the lower clip binds
        acc1 += __logf(fmaxf(x1, 1e-8f));
        acc2 += __logf(fmaxf(x2, 1e-8f));
        acc3 += __logf(fmaxf(x3, 1e-8f));
    }

    float lsum = (mk.x > 0 ? acc0 : 0.f) + (mk.y > 0 ? acc1 : 0.f)
               + (mk.z > 0 ? acc2 : 0.f) + (mk.w > 0 ? acc3 : 0.f);
    int   lcnt = (mk.x > 0) + (mk.y > 0) + (mk.z > 0) + (mk.w > 0);

    // ---- wave64 reduce, then LDS, then publish one partial per block ----
    #pragma unroll
    for (int off = 32; off > 0; off >>= 1) {
        lsum += __shfl_down(lsum, off);
        lcnt += __shfl_down(lcnt, off);
    }
    __shared__ float swave[kBlock / 64];
    __shared__ int   cwave[kBlock / 64];
    __shared__ bool  amLast;
    const int lane = threadIdx.x & 63;
    const int wid  = threadIdx.x >> 6;
    if (lane == 0) { swave[wid] = lsum; cwave[wid] = lcnt; }
    __syncthreads();
    if (threadIdx.x == 0) {
        // Agent-scope stores so the partial is device-visible regardless of
        // which XCD's L2 this block writes through (G16: per-XCD L2s are
        // not cross-coherent).
        __hip_atomic_store(&bsum[blockIdx.x],
                           swave[0] + swave[1] + swave[2] + swave[3],
                           __ATOMIC_RELAXED, __HIP_MEMORY_SCOPE_AGENT);
        __hip_atomic_store(&bcnt[blockIdx.x],
                           cwave[0] + cwave[1] + cwave[2] + cwave[3],
                           __ATOMIC_RELAXED, __HIP_MEMORY_SCOPE_AGENT);
        __threadfence();                         // release: partials visible
        unsigned old = atomicAdd(ticket, 1u);    // device-scope by default
        amLast = (old == (unsigned)(kGrid - 1));
    }
    __syncthreads();
    if (!amLast) return;

    // ---- last arriving block: fold all 1024 partials (deterministic,
    // same double-precision order as the old ordloss_reduce kernel) ----
    __threadfence();                             // acquire: invalidate stale lines

    const int t4 = threadIdx.x * 4;
    const float a0 = __hip_atomic_load(&bsum[t4 + 0], __ATOMIC_RELAXED, __HIP_MEMORY_SCOPE_AGENT);
    const float a1 = __hip_atomic_load(&bsum[t4 + 1], __ATOMIC_RELAXED, __HIP_MEMORY_SCOPE_AGENT);
    const float a2 = __hip_atomic_load(&bsum[t4 + 2], __ATOMIC_RELAXED, __HIP_MEMORY_SCOPE_AGENT);
    const float a3 = __hip_atomic_load(&bsum[t4 + 3], __ATOMIC_RELAXED, __HIP_MEMORY_SCOPE_AGENT);
    const int   b0 = __hip_atomic_load(&bcnt[t4 + 0], __ATOMIC_RELAXED, __HIP_MEMORY_SCOPE_AGENT);
    const int   b1 = __hip_atomic_load(&bcnt[t4 + 1], __ATOMIC_RELAXED, __HIP_MEMORY_SCOPE_AGENT);
    const int   b2 = __hip_atomic_load(&bcnt[t4 + 2], __ATOMIC_RELAXED, __HIP_MEMORY_SCOPE_AGENT);
    const int   b3 = __hip_atomic_load(&bcnt[t4 + 3], __ATOMIC_RELAXED, __HIP_MEMORY_SCOPE_AGENT);

    double s = (double)a0 + a1 + a2 + a3;
    long   c = (long)b0 + b1 + b2 + b3;
    #pragma unroll
    for (int off = 32; off > 0; off >>= 1) {
        s += __shfl_down(s, off);
        c += __shfl_down(c, off);
    }
    __shared__ double sw[kBlock / 64];
    __shared__ long   cw[kBlock / 64];
    if (lane == 0) { sw[wid] = s; cw[wid] = c; }
    __syncthreads();
    if (threadIdx.x == 0) {
        double S = sw[0] + sw[1] + sw[2] + sw[3];
        long   C = cw[0] + cw[1] + cw[2] + cw[3];
        out[0] = (float)(S / (double)(-C));
    }
}

extern "C" void kernel_launch(void* const* d_in, const int* in_sizes, int n_in,
                              void* d_out, int out_size, void* d_ws, size_t ws_size,
                              hipStream_t stream) {
    const float* pred   = (const float*)d_in[0];
    const int*   target = (const int*)d_in[1];
    const int*   mask   = (const int*)d_in[2];
    float*       bsum   = (float*)d_ws;                                  // 1024 floats
    int*         bcnt   = (int*)((char*)d_ws + kGrid * sizeof(float));   // 1024 ints
    unsigned*    ticket = (unsigned*)((char*)d_ws + 2 * kGrid * sizeof(float));
    float*       out    = (float*)d_out;

    // ws is re-poisoned by the harness each iteration: the ticket must be
    // zeroed explicitly (4-byte memset node, ~1 us dispatch).
    hipMemsetAsync(ticket, 0, sizeof(unsigned), stream);
    ordloss_fused<<<kGrid, kBlock, 0, stream>>>(pred, target, mask,
                                                bsum, bcnt, ticket, out);
}

// Round 2
// 136.337 us; speedup vs baseline: 1.3349x; 1.3349x over previous
//
#include <hip/hip_runtime.h>

// OrdLoss: N=2, C=16, D=32, H=128, W=128
// out = [ sum_{valid m} ( sum_{c<=t} log(clip(p)) + sum_{c>t} log(clip(1-p)) ) ] / ( -sum(valid) )
//
// REVERT to best-measured two-dispatch structure (135.9 us, R0).
//
// Session record:
//  - R2 prefetch / R3 +sched_barrier / R4 transpose / R5 grid-stride:
//    137.2 / 137.3 / 141.6 / 147.0 us (prior session).
//  - R0 re-measure of R2 structure: 135.9 us (best).
//  - R6 last-block-done fusion: 181.99 us. FAILED — fused epilogue dropped
//    the kernel to 32 VGPRs (compiler serialized the 18-load stream, killing
//    MLP: 56 us @ 8% HBM), and per-block agent-scope fences + hot-line
//    atomics added serialization. Do not re-attempt single-dispatch fusion.
//
// Per-iteration budget: ~120 us harness poison fills (3 x ~40 us, 268 MB,
// 82-84% HBM peak — untouchable) + main kernel at the 76 MB compulsory
// traffic floor (~13 us @ 6.3 TB/s) + ~3 us reduce dispatch. This is the
// structural floor.
//
// Structure: 1024 blocks x 256 threads, 4 voxels/thread. All 18 loads
// (16 pred float4 @ 2 MiB channel stride + target-ch0 int4 + mask int4)
// issued before compute; 64 logs over 4 independent accumulator chains;
// wave64 shuffle reduce -> LDS -> one plain store per block; 1-block
// reduce kernel folds 1024 partials in double and writes s / (-S).

constexpr int  kC     = 16;
constexpr int  kDHW   = 32 * 128 * 128;   // 524288 = 2^19
constexpr long kM     = 2L * kDHW;        // 1048576 voxels
constexpr int  kBlock = 256;
constexpr int  kVox   = 4;                // voxels per thread (one float4 per channel)
constexpr int  kGrid  = (int)(kM / kVox / kBlock);   // 1024 blocks

__global__ __launch_bounds__(kBlock)
void ordloss_main(const float* __restrict__ pred,
                  const int*   __restrict__ target,
                  const int*   __restrict__ mask,
                  float*       __restrict__ bsum,
                  int*         __restrict__ bcnt) {
    const int  tid  = blockIdx.x * kBlock + threadIdx.x;
    const long base = (long)tid * kVox;
    const int  n    = (int)(base >> 19);             // base / kDHW
    const int  sp   = (int)(base & (kDHW - 1));

    // ---- issue ALL loads up front ----
    const int4 mk = *reinterpret_cast<const int4*>(mask + base);
    const int4 tg = *reinterpret_cast<const int4*>(target + ((size_t)n << 23) + sp);
    const float* pb = pred + ((size_t)n << 23) + sp; // n*16*kDHW
    float4 p[kC];
    #pragma unroll
    for (int c = 0; c < kC; ++c)
        p[c] = *reinterpret_cast<const float4*>(pb + ((size_t)c << 19));

    // ---- compute: 64 logs, 4 independent accumulator chains ----
    float acc0 = 0.f, acc1 = 0.f, acc2 = 0.f, acc3 = 0.f;
    #pragma unroll
    for (int c = 0; c < kC; ++c) {
        float x0 = (c <= tg.x) ? p[c].x : 1.0f - p[c].x;
        float x1 = (c <= tg.y) ? p[c].y : 1.0f - p[c].y;
        float x2 = (c <= tg.z) ? p[c].z : 1.0f - p[c].z;
        float x3 = (c <= tg.w) ? p[c].w : 1.0f - p[c].w;
        acc0 += __logf(fmaxf(x0, 1e-8f));   // p in [0,1): only the lower clip binds
        acc1 += __logf(fmaxf(x1, 1e-8f));
        acc2 += __logf(fmaxf(x2, 1e-8f));
        acc3 += __logf(fmaxf(x3, 1e-8f));
    }

    float lsum = (mk.x > 0 ? acc0 : 0.f) + (mk.y > 0 ? acc1 : 0.f)
               + (mk.z > 0 ? acc2 : 0.f) + (mk.w > 0 ? acc3 : 0.f);
    int   lcnt = (mk.x > 0) + (mk.y > 0) + (mk.z > 0) + (mk.w > 0);

    // ---- wave64 reduce, then LDS, then one plain store per block ----
    #pragma unroll
    for (int off = 32; off > 0; off >>= 1) {
        lsum += __shfl_down(lsum, off);
        lcnt += __shfl_down(lcnt, off);
    }
    __shared__ float swave[kBlock / 64];
    __shared__ int   cwave[kBlock / 64];
    const int lane = threadIdx.x & 63;
    const int wid  = threadIdx.x >> 6;
    if (lane == 0) { swave[wid] = lsum; cwave[wid] = lcnt; }
    __syncthreads();
    if (threadIdx.x == 0) {
        bsum[blockIdx.x] = swave[0] + swave[1] + swave[2] + swave[3];
        bcnt[blockIdx.x] = cwave[0] + cwave[1] + cwave[2] + cwave[3];
    }
}

// 1 block, 256 threads: reduce 1024 partials, write the scalar.
__global__ __launch_bounds__(kBlock)
void ordloss_reduce(const float* __restrict__ bsum,
                    const int*   __restrict__ bcnt,
                    float*       __restrict__ out) {
    const float4 s4 = *reinterpret_cast<const float4*>(bsum + threadIdx.x * 4);
    const int4   c4 = *reinterpret_cast<const int4*>(bcnt + threadIdx.x * 4);
    double s = (double)s4.x + s4.y + s4.z + s4.w;
    long   c = (long)c4.x + c4.y + c4.z + c4.w;
    #pragma unroll
    for (int off = 32; off > 0; off >>= 1) {
        s += __shfl_down(s, off);
        c += __shfl_down(c, off);
    }
    __shared__ double sw[kBlock / 64];
    __shared__ long   cw[kBlock / 64];
    const int lane = threadIdx.x & 63;
    const int wid  = threadIdx.x >> 6;
    if (lane == 0) { sw[wid] = s; cw[wid] = c; }
    __syncthreads();
    if (threadIdx.x == 0) {
        double S = sw[0] + sw[1] + sw[2] + sw[3];
        long   C = cw[0] + cw[1] + cw[2] + cw[3];
        out[0] = (float)(S / (double)(-C));
    }
}

extern "C" void kernel_launch(void* const* d_in, const int* in_sizes, int n_in,
                              void* d_out, int out_size, void* d_ws, size_t ws_size,
                              hipStream_t stream) {
    const float* pred   = (const float*)d_in[0];
    const int*   target = (const int*)d_in[1];
    const int*   mask   = (const int*)d_in[2];
    float*       bsum   = (float*)d_ws;               // 1024 floats
    int*         bcnt   = (int*)((char*)d_ws + kGrid * sizeof(float)); // 1024 ints
    float*       out    = (float*)d_out;

    ordloss_main<<<kGrid, kBlock, 0, stream>>>(pred, target, mask, bsum, bcnt);
    ordloss_reduce<<<1, kBlock, 0, stream>>>(bsum, bcnt, out);
}